// Round 2
// baseline (2058.468 us; speedup 1.0000x reference)
//
#include <hip/hip_runtime.h>
#include <hip/hip_bf16.h>

#define N_NODES 100000
#define EMB     64
#define N_EDGES 1200000
#define ALPHA   0.25f

// ---------------------------------------------------------------------------
// Format detection (single block): the harness contract is ambiguous about
// whether edge_mask (bool) is stored as 1-byte bool or widened to int32, and
// whether edge_index (declared int64, but JAX-x64-off usually yields int32)
// is 4 or 8 bytes per element. Detect both from the data:
//  - mask: int32 storage of 0/1 values has zero bytes at every offset i%4!=0.
//    1-byte bool storage (~50% ones) has nonzero bytes there.
//  - index: int64 storage of values < 100000 has zero high words (odd int32
//    positions). int32 storage has random indices there (P(all-zero) ~ 0).
// flags[0] = 1 if mask is 1-byte bool;  flags[1] = 1 if indices are int64.
// ---------------------------------------------------------------------------
__global__ void k_detect(const unsigned char* maskB, const int* idx, int* flags) {
    __shared__ int sm, si;
    if (threadIdx.x == 0) { sm = 0; si = 0; }
    __syncthreads();
    int m = 0, iv = 0;
    for (int i = threadIdx.x; i < N_EDGES; i += blockDim.x)
        if ((i & 3) && maskB[i]) m = 1;
    for (int i = threadIdx.x; i < 4096; i += blockDim.x)
        if (idx[2 * i + 1] != 0) iv = 1;
    if (m)  atomicOr(&sm, 1);
    if (iv) atomicOr(&si, 1);
    __syncthreads();
    if (threadIdx.x == 0) { flags[0] = sm; flags[1] = si ? 0 : 1; }
}

__device__ __forceinline__ int idx_row(const int* idx, int i64, int e) {
    return i64 ? idx[2 * e] : idx[e];
}
__device__ __forceinline__ int idx_col(const int* idx, int i64, int e) {
    return i64 ? idx[2 * (N_EDGES + e)] : idx[N_EDGES + e];
}

// w[e] = edge_attr[e] * mask[e];  deg[col[e]] += w[e]
__global__ void k_degw(const float* __restrict__ ea, const void* maskp,
                       const int* __restrict__ idx, const int* __restrict__ flags,
                       float* __restrict__ w, float* __restrict__ deg) {
    int e = blockIdx.x * blockDim.x + threadIdx.x;
    if (e >= N_EDGES) return;
    int mbool = flags[0], i64 = flags[1];
    int m = mbool ? (int)((const unsigned char*)maskp)[e] : ((const int*)maskp)[e];
    float wv = (m != 0) ? ea[e] : 0.0f;
    w[e] = wv;
    if (wv != 0.0f) {
        int c = idx_col(idx, i64, e);
        if ((unsigned)c < N_NODES) atomicAdd(&deg[c], wv);
    }
}

// deg -> dinv in place
__global__ void k_dinv(float* deg) {
    int i = blockIdx.x * blockDim.x + threadIdx.x;
    if (i >= N_NODES) return;
    float d = deg[i];
    deg[i] = (d > 0.0f) ? rsqrtf(d) : 0.0f;
}

// w[e] -> norm[e] = dinv[row]*w*dinv[col] in place
__global__ void k_norm(const int* __restrict__ idx, const int* __restrict__ flags,
                       const float* __restrict__ dinv, float* __restrict__ w) {
    int e = blockIdx.x * blockDim.x + threadIdx.x;
    if (e >= N_EDGES) return;
    float wv = w[e];
    if (wv == 0.0f) return;
    int i64 = flags[1];
    int r = idx_row(idx, i64, e);
    int c = idx_col(idx, i64, e);
    if ((unsigned)r >= N_NODES || (unsigned)c >= N_NODES) { w[e] = 0.0f; return; }
    w[e] = dinv[r] * wv * dinv[c];
}

// h0 = x; acc(=d_out) = ALPHA * x
__global__ void k_init(const float* __restrict__ x, float* __restrict__ h,
                       float* __restrict__ acc) {
    int i = blockIdx.x * blockDim.x + threadIdx.x;
    if (i >= N_NODES * EMB) return;
    float v = x[i];
    h[i] = v;
    acc[i] = ALPHA * v;
}

// One 64-lane wave per edge, lane = embedding dim.
// hdst[col[e]][d] += norm[e] * hsrc[row[e]][d]
__global__ void k_scatter(const float* __restrict__ norm, const int* __restrict__ idx,
                          const int* __restrict__ flags,
                          const float* __restrict__ hsrc, float* __restrict__ hdst) {
    int t = blockIdx.x * blockDim.x + threadIdx.x;
    int e = t >> 6;
    int d = t & 63;
    if (e >= N_EDGES) return;
    float nm = norm[e];
    if (nm == 0.0f) return;                 // wave-uniform: masked edges skip entirely
    int i64 = flags[1];
    int r = idx_row(idx, i64, e);
    int c = idx_col(idx, i64, e);
    if ((unsigned)r >= N_NODES || (unsigned)c >= N_NODES) return;
    atomicAdd(&hdst[c * EMB + d], nm * hsrc[r * EMB + d]);
}

// acc += ALPHA * h
__global__ void k_accum(const float* __restrict__ h, float* __restrict__ acc) {
    int i = blockIdx.x * blockDim.x + threadIdx.x;
    if (i >= N_NODES * EMB) return;
    acc[i] += ALPHA * h[i];
}

extern "C" void kernel_launch(void* const* d_in, const int* in_sizes, int n_in,
                              void* d_out, int out_size, void* d_ws, size_t ws_size,
                              hipStream_t stream) {
    const float* x   = (const float*)d_in[0];
    const float* ea  = (const float*)d_in[1];
    const int*   idx = (const int*)d_in[2];
    const void*  msk = d_in[3];
    float*       acc = (float*)d_out;   // fp32 output doubles as the accumulator

    char* ws = (char*)d_ws;
    size_t off = 0;
    auto alloc = [&](size_t bytes) -> void* {
        void* p = ws + off;
        off = (off + bytes + 255) & ~(size_t)255;
        return p;
    };
    int*   flags = (int*)  alloc(64);
    float* w     = (float*)alloc(sizeof(float) * N_EDGES);
    float* deg   = (float*)alloc(sizeof(float) * N_NODES);
    float* hA    = (float*)alloc(sizeof(float) * (size_t)N_NODES * EMB);
    float* hB    = (float*)alloc(sizeof(float) * (size_t)N_NODES * EMB);

    const int B = 256;
    const int gE  = (N_EDGES + B - 1) / B;
    const int gN  = (N_NODES + B - 1) / B;
    const int gND = (N_NODES * EMB + B - 1) / B;
    const int gS  = (N_EDGES * 64 + B - 1) / B;   // 300000 blocks

    hipMemsetAsync(deg, 0, sizeof(float) * N_NODES, stream);
    k_detect<<<1, 256, 0, stream>>>((const unsigned char*)msk, idx, flags);
    k_degw  <<<gE, B, 0, stream>>>(ea, msk, idx, flags, w, deg);
    k_dinv  <<<gN, B, 0, stream>>>(deg);
    k_norm  <<<gE, B, 0, stream>>>(idx, flags, deg, w);
    k_init  <<<gND, B, 0, stream>>>(x, hA, acc);

    float* src = hA;
    float* dst = hB;
    for (int l = 0; l < 3; ++l) {
        hipMemsetAsync(dst, 0, sizeof(float) * (size_t)N_NODES * EMB, stream);
        k_scatter<<<gS, B, 0, stream>>>(w, idx, flags, src, dst);
        k_accum  <<<gND, B, 0, stream>>>(dst, acc);
        float* tmp = src; src = dst; dst = tmp;
    }
}

// Round 3
// 763.068 us; speedup vs baseline: 2.6976x; 2.6976x over previous
//
#include <hip/hip_runtime.h>
#include <hip/hip_bf16.h>

#define N_NODES 100000
#define EMB     64
#define N_EDGES 1200000
#define ALPHA   0.25f

// ---------------------------------------------------------------------------
// Format detection — SAMPLED (R2 post-mortem: full-scan single-block version
// was 1.4-2.0 ms, 97% of runtime, 0.05% occupancy).
//  - mask: int32 storage of 0/1 values has zero bytes at every offset i%4!=0.
//    Sample 16 KB: bool storage (~50% ones) trips with P(miss) ~ 2^-12288.
//    All-zero mask degenerates to "int32" but then w==0 either way -> same out.
//  - index: int64 storage of values <100000 has zero high words at odd int32
//    positions. 4096 samples of random int32 indices are ~never all zero.
// flags[0] = 1 if mask is 1-byte bool;  flags[1] = 1 if indices are int64.
// ---------------------------------------------------------------------------
__global__ void k_detect(const unsigned char* maskB, const int* idx, int* flags) {
    __shared__ int sm, si;
    if (threadIdx.x == 0) { sm = 0; si = 0; }
    __syncthreads();
    int m = 0, iv = 0;
    for (int i = threadIdx.x; i < 16384; i += blockDim.x)
        if ((i & 3) && maskB[i]) m = 1;
    for (int i = threadIdx.x; i < 4096; i += blockDim.x)
        if (idx[2 * i + 1] != 0) iv = 1;
    if (m)  atomicOr(&sm, 1);
    if (iv) atomicOr(&si, 1);
    __syncthreads();
    if (threadIdx.x == 0) { flags[0] = sm; flags[1] = si ? 0 : 1; }
}

__device__ __forceinline__ int idx_row(const int* idx, int i64, int e) {
    return i64 ? idx[2 * e] : idx[e];
}
__device__ __forceinline__ int idx_col(const int* idx, int i64, int e) {
    return i64 ? idx[2 * (N_EDGES + e)] : idx[N_EDGES + e];
}

// w[e] = edge_attr[e] * mask[e];  deg[col[e]] += w[e]
__global__ void k_degw(const float* __restrict__ ea, const void* maskp,
                       const int* __restrict__ idx, const int* __restrict__ flags,
                       float* __restrict__ w, float* __restrict__ deg) {
    int e = blockIdx.x * blockDim.x + threadIdx.x;
    if (e >= N_EDGES) return;
    int mbool = flags[0], i64 = flags[1];
    int m = mbool ? (int)((const unsigned char*)maskp)[e] : ((const int*)maskp)[e];
    float wv = (m != 0) ? ea[e] : 0.0f;
    w[e] = wv;
    if (wv != 0.0f) {
        int c = idx_col(idx, i64, e);
        if ((unsigned)c < N_NODES) atomicAdd(&deg[c], wv);
    }
}

// deg -> dinv in place
__global__ void k_dinv(float* deg) {
    int i = blockIdx.x * blockDim.x + threadIdx.x;
    if (i >= N_NODES) return;
    float d = deg[i];
    deg[i] = (d > 0.0f) ? rsqrtf(d) : 0.0f;
}

// w[e] -> norm[e] = dinv[row]*w*dinv[col] in place
__global__ void k_norm(const int* __restrict__ idx, const int* __restrict__ flags,
                       const float* __restrict__ dinv, float* __restrict__ w) {
    int e = blockIdx.x * blockDim.x + threadIdx.x;
    if (e >= N_EDGES) return;
    float wv = w[e];
    if (wv == 0.0f) return;
    int i64 = flags[1];
    int r = idx_row(idx, i64, e);
    int c = idx_col(idx, i64, e);
    if ((unsigned)r >= N_NODES || (unsigned)c >= N_NODES) { w[e] = 0.0f; return; }
    w[e] = dinv[r] * wv * dinv[c];
}

// h0 = x; acc(=d_out) = ALPHA * x
__global__ void k_init(const float* __restrict__ x, float* __restrict__ h,
                       float* __restrict__ acc) {
    int i = blockIdx.x * blockDim.x + threadIdx.x;
    if (i >= N_NODES * EMB) return;
    float v = x[i];
    h[i] = v;
    acc[i] = ALPHA * v;
}

// One 64-lane wave per edge, lane = embedding dim.
// hdst[col[e]][d] += norm[e] * hsrc[row[e]][d]
__global__ void k_scatter(const float* __restrict__ norm, const int* __restrict__ idx,
                          const int* __restrict__ flags,
                          const float* __restrict__ hsrc, float* __restrict__ hdst) {
    int t = blockIdx.x * blockDim.x + threadIdx.x;
    int e = t >> 6;
    int d = t & 63;
    if (e >= N_EDGES) return;
    float nm = norm[e];
    if (nm == 0.0f) return;                 // wave-uniform: masked edges skip entirely
    int i64 = flags[1];
    int r = idx_row(idx, i64, e);
    int c = idx_col(idx, i64, e);
    if ((unsigned)r >= N_NODES || (unsigned)c >= N_NODES) return;
    atomicAdd(&hdst[c * EMB + d], nm * hsrc[r * EMB + d]);
}

// acc += ALPHA * h
__global__ void k_accum(const float* __restrict__ h, float* __restrict__ acc) {
    int i = blockIdx.x * blockDim.x + threadIdx.x;
    if (i >= N_NODES * EMB) return;
    acc[i] += ALPHA * h[i];
}

extern "C" void kernel_launch(void* const* d_in, const int* in_sizes, int n_in,
                              void* d_out, int out_size, void* d_ws, size_t ws_size,
                              hipStream_t stream) {
    const float* x   = (const float*)d_in[0];
    const float* ea  = (const float*)d_in[1];
    const int*   idx = (const int*)d_in[2];
    const void*  msk = d_in[3];
    float*       acc = (float*)d_out;   // fp32 output doubles as the accumulator

    char* ws = (char*)d_ws;
    size_t off = 0;
    auto alloc = [&](size_t bytes) -> void* {
        void* p = ws + off;
        off = (off + bytes + 255) & ~(size_t)255;
        return p;
    };
    int*   flags = (int*)  alloc(64);
    float* w     = (float*)alloc(sizeof(float) * N_EDGES);
    float* deg   = (float*)alloc(sizeof(float) * N_NODES);
    float* hA    = (float*)alloc(sizeof(float) * (size_t)N_NODES * EMB);
    float* hB    = (float*)alloc(sizeof(float) * (size_t)N_NODES * EMB);

    const int B = 256;
    const int gE  = (N_EDGES + B - 1) / B;
    const int gN  = (N_NODES + B - 1) / B;
    const int gND = (N_NODES * EMB + B - 1) / B;
    const int gS  = (N_EDGES * 64 + B - 1) / B;   // 300000 blocks

    hipMemsetAsync(deg, 0, sizeof(float) * N_NODES, stream);
    k_detect<<<1, 256, 0, stream>>>((const unsigned char*)msk, idx, flags);
    k_degw  <<<gE, B, 0, stream>>>(ea, msk, idx, flags, w, deg);
    k_dinv  <<<gN, B, 0, stream>>>(deg);
    k_norm  <<<gE, B, 0, stream>>>(idx, flags, deg, w);
    k_init  <<<gND, B, 0, stream>>>(x, hA, acc);

    float* src = hA;
    float* dst = hB;
    for (int l = 0; l < 3; ++l) {
        hipMemsetAsync(dst, 0, sizeof(float) * (size_t)N_NODES * EMB, stream);
        k_scatter<<<gS, B, 0, stream>>>(w, idx, flags, src, dst);
        k_accum  <<<gND, B, 0, stream>>>(dst, acc);
        float* tmp = src; src = dst; dst = tmp;
    }
}

// Round 5
// 642.933 us; speedup vs baseline: 3.2017x; 1.1869x over previous
//
#include <hip/hip_runtime.h>
#include <hip/hip_bf16.h>

#define N_NODES 100000
#define EMB     64
#define N_EDGES 1200000
#define ALPHA   0.25f
#define SCAN_T  1024

// ---------------------------------------------------------------------------
// Format detection — SAMPLED (R2: full scan was 1.4-2.0 ms @ 0.05% occupancy).
// flags[0] = 1 if mask is 1-byte bool;  flags[1] = 1 if indices are int64.
// ---------------------------------------------------------------------------
__global__ void k_detect(const unsigned char* maskB, const int* idx, int* flags) {
    __shared__ int sm, si;
    if (threadIdx.x == 0) { sm = 0; si = 0; }
    __syncthreads();
    int m = 0, iv = 0;
    for (int i = threadIdx.x; i < 16384; i += blockDim.x)
        if ((i & 3) && maskB[i]) m = 1;
    for (int i = threadIdx.x; i < 4096; i += blockDim.x)
        if (idx[2 * i + 1] != 0) iv = 1;
    if (m)  atomicOr(&sm, 1);
    if (iv) atomicOr(&si, 1);
    __syncthreads();
    if (threadIdx.x == 0) { flags[0] = sm; flags[1] = si ? 0 : 1; }
}

__device__ __forceinline__ int idx_row(const int* idx, int i64, int e) {
    return i64 ? idx[2 * e] : idx[e];
}
__device__ __forceinline__ int idx_col(const int* idx, int i64, int e) {
    return i64 ? idx[2 * (N_EDGES + e)] : idx[N_EDGES + e];
}
__device__ __forceinline__ int edge_mask(const void* maskp, int mbool, int e) {
    return mbool ? (int)((const unsigned char*)maskp)[e] : ((const int*)maskp)[e];
}

// Histogram pass: deg[col] += w (weighted degree), cnt[col] += 1 (CSR counts).
__global__ void k_degw(const float* __restrict__ ea, const void* maskp,
                       const int* __restrict__ idx, const int* __restrict__ flags,
                       float* __restrict__ deg, int* __restrict__ cnt) {
    int e = blockIdx.x * blockDim.x + threadIdx.x;
    if (e >= N_EDGES) return;
    int mbool = flags[0], i64 = flags[1];
    if (!edge_mask(maskp, mbool, e)) return;
    float wv = ea[e];
    if (wv == 0.0f) return;
    int c = idx_col(idx, i64, e);
    if ((unsigned)c >= N_NODES) return;
    atomicAdd(&deg[c], wv);
    atomicAdd(&cnt[c], 1);
}

// deg -> dinv in place
__global__ void k_dinv(float* deg) {
    int i = blockIdx.x * blockDim.x + threadIdx.x;
    if (i >= N_NODES) return;
    float d = deg[i];
    deg[i] = (d > 0.0f) ? rsqrtf(d) : 0.0f;
}

// Single-block exclusive scan over cnt -> row_ptr[0..N]; zeroes cnt for reuse
// as the fill cursor. 1024 threads x 98-element chunks; Hillis-Steele in LDS.
__global__ void k_scan(int* __restrict__ cnt, int* __restrict__ row_ptr) {
    __shared__ int sh[SCAN_T];
    int tid = threadIdx.x;
    const int CH = (N_NODES + SCAN_T - 1) / SCAN_T;
    int beg = tid * CH;
    int end = beg + CH; if (end > N_NODES) end = N_NODES;
    int s = 0;
    for (int i = beg; i < end; ++i) s += cnt[i];
    sh[tid] = s;
    __syncthreads();
    for (int d = 1; d < SCAN_T; d <<= 1) {
        int v = (tid >= d) ? sh[tid - d] : 0;
        __syncthreads();
        sh[tid] += v;
        __syncthreads();
    }
    int off = sh[tid] - s;          // exclusive prefix of this chunk
    for (int i = beg; i < end; ++i) {
        int c = cnt[i];
        row_ptr[i] = off;
        cnt[i] = 0;                 // becomes the fill cursor
        off += c;
    }
    if (end >= N_NODES) row_ptr[N_NODES] = off;  // all writers agree on total
}

// Fill CSR: for each active edge, slot p = row_ptr[col] + cursor[col]++.
// Inserts EXACTLY cnt[col] entries per node (OOB rows insert nm=0) so
// row_ptr[n+1] is a valid end pointer. csr entry packs (norm bits, src row).
// R4 hardening: bounds-check p so any latent count/fill mismatch shows up as
// a wrong answer (absmax), never a device fault.
__global__ void k_fill(const float* __restrict__ ea, const void* maskp,
                       const int* __restrict__ idx, const int* __restrict__ flags,
                       const float* __restrict__ dinv, const int* __restrict__ row_ptr,
                       int* __restrict__ cursor, int2* __restrict__ csr) {
    int e = blockIdx.x * blockDim.x + threadIdx.x;
    if (e >= N_EDGES) return;
    int mbool = flags[0], i64 = flags[1];
    if (!edge_mask(maskp, mbool, e)) return;
    float wv = ea[e];
    if (wv == 0.0f) return;
    int c = idx_col(idx, i64, e);
    if ((unsigned)c >= N_NODES) return;
    int r = idx_row(idx, i64, e);
    int rok = (unsigned)r < N_NODES;
    float nm = dinv[c] * wv * (rok ? dinv[r] : 0.0f);
    int p = row_ptr[c] + atomicAdd(&cursor[c], 1);
    if ((unsigned)p < N_EDGES)
        csr[p] = make_int2(__float_as_int(nm), rok ? r : 0);
}

// One 64-lane wave per node, lane = dim. Register accumulation, no atomics.
// mode 0: hdst=s, acc=ALPHA*(x+s)   (layer 1, src = x)
// mode 1: hdst=s, acc+=ALPHA*s      (layer 2)
// mode 2: acc+=ALPHA*s              (layer 3, no hdst)
// R4 hardening: clamp [beg,end) against row_ptr[N]/N_EDGES and skip bad src
// ids — indirect reads can never fault.
__global__ __launch_bounds__(256) void k_gather(
        const int* __restrict__ row_ptr, const int2* __restrict__ csr,
        const float* __restrict__ hsrc, float* __restrict__ hdst,
        const float* __restrict__ x, float* __restrict__ acc, int mode) {
    int t = blockIdx.x * blockDim.x + threadIdx.x;
    int n = t >> 6;
    int d = t & 63;
    if (n >= N_NODES) return;
    int total = row_ptr[N_NODES];
    if (total > N_EDGES) total = N_EDGES;
    int beg = row_ptr[n], end = row_ptr[n + 1];
    if (beg < 0) beg = 0;
    if (end > total) end = total;
    float s = 0.0f;
    for (int j = beg; j < end; ++j) {
        int2 p = csr[j];                       // wave-uniform -> broadcast
        if ((unsigned)p.y >= N_NODES) continue;
        s += __int_as_float(p.x) * hsrc[(size_t)p.y * EMB + d];
    }
    size_t o = (size_t)n * EMB + d;
    if (mode == 0)      { hdst[o] = s; acc[o] = ALPHA * (x[o] + s); }
    else if (mode == 1) { hdst[o] = s; acc[o] += ALPHA * s; }
    else                { acc[o] += ALPHA * s; }
}

extern "C" void kernel_launch(void* const* d_in, const int* in_sizes, int n_in,
                              void* d_out, int out_size, void* d_ws, size_t ws_size,
                              hipStream_t stream) {
    const float* x   = (const float*)d_in[0];
    const float* ea  = (const float*)d_in[1];
    const int*   idx = (const int*)d_in[2];
    const void*  msk = d_in[3];
    float*       acc = (float*)d_out;   // fp32 output doubles as the accumulator

    char* ws = (char*)d_ws;
    size_t off = 0;
    auto alloc = [&](size_t bytes) -> void* {
        void* p = ws + off;
        off = (off + bytes + 255) & ~(size_t)255;
        return p;
    };
    int*   flags   = (int*)  alloc(64);
    float* deg     = (float*)alloc(sizeof(float) * N_NODES);      // then dinv
    int*   cnt     = (int*)  alloc(sizeof(int)   * N_NODES);      // then cursor
    int*   row_ptr = (int*)  alloc(sizeof(int)   * (N_NODES + 1));
    int2*  csr     = (int2*) alloc(sizeof(int2)  * N_EDGES);
    float* hA      = (float*)alloc(sizeof(float) * (size_t)N_NODES * EMB);
    float* hB      = (float*)alloc(sizeof(float) * (size_t)N_NODES * EMB);

    const int B = 256;
    const int gE = (N_EDGES + B - 1) / B;
    const int gN = (N_NODES + B - 1) / B;
    const int gG = (N_NODES * EMB + B - 1) / B;   // 25000 blocks, 1 wave/node

    // deg and cnt are adjacent (modulo 256-pad) -> one memset covers both.
    hipMemsetAsync(deg, 0, (size_t)((char*)row_ptr - (char*)deg), stream);
    k_detect<<<1, 256, 0, stream>>>((const unsigned char*)msk, idx, flags);
    k_degw  <<<gE, B, 0, stream>>>(ea, msk, idx, flags, deg, cnt);
    k_dinv  <<<gN, B, 0, stream>>>(deg);
    k_scan  <<<1, SCAN_T, 0, stream>>>(cnt, row_ptr);
    k_fill  <<<gE, B, 0, stream>>>(ea, msk, idx, flags, deg, row_ptr, cnt, csr);

    k_gather<<<gG, B, 0, stream>>>(row_ptr, csr, x,  hA, x, acc, 0);
    k_gather<<<gG, B, 0, stream>>>(row_ptr, csr, hA, hB, x, acc, 1);
    k_gather<<<gG, B, 0, stream>>>(row_ptr, csr, hB, hB, x, acc, 2);
}

// Round 6
// 421.390 us; speedup vs baseline: 4.8849x; 1.5257x over previous
//
#include <hip/hip_runtime.h>
#include <hip/hip_bf16.h>

#define N_NODES 100000
#define EMB     64
#define N_EDGES 1200000
#define ALPHA   0.25f
#define SCAN_CHUNK 1024
#define NPART ((N_NODES + SCAN_CHUNK - 1) / SCAN_CHUNK)   // 98

// ---------------------------------------------------------------------------
// Format detection — SAMPLED (R2: full scan was 1.4-2.0 ms @ 0.05% occupancy).
// flags[0] = 1 if mask is 1-byte bool;  flags[1] = 1 if indices are int64.
// ---------------------------------------------------------------------------
__global__ void k_detect(const unsigned char* maskB, const int* idx, int* flags) {
    __shared__ int sm, si;
    if (threadIdx.x == 0) { sm = 0; si = 0; }
    __syncthreads();
    int m = 0, iv = 0;
    for (int i = threadIdx.x; i < 16384; i += blockDim.x)
        if ((i & 3) && maskB[i]) m = 1;
    for (int i = threadIdx.x; i < 4096; i += blockDim.x)
        if (idx[2 * i + 1] != 0) iv = 1;
    if (m)  atomicOr(&sm, 1);
    if (iv) atomicOr(&si, 1);
    __syncthreads();
    if (threadIdx.x == 0) { flags[0] = sm; flags[1] = si ? 0 : 1; }
}

__device__ __forceinline__ int idx_row(const int* idx, int i64, int e) {
    return i64 ? idx[2 * e] : idx[e];
}
__device__ __forceinline__ int idx_col(const int* idx, int i64, int e) {
    return i64 ? idx[2 * (N_EDGES + e)] : idx[N_EDGES + e];
}
__device__ __forceinline__ int edge_mask(const void* maskp, int mbool, int e) {
    return mbool ? (int)((const unsigned char*)maskp)[e] : ((const int*)maskp)[e];
}

// Histogram pass: deg[col] += w (weighted degree), cnt[col] += 1 (CSR counts).
__global__ void k_degw(const float* __restrict__ ea, const void* maskp,
                       const int* __restrict__ idx, const int* __restrict__ flags,
                       float* __restrict__ deg, int* __restrict__ cnt) {
    int e = blockIdx.x * blockDim.x + threadIdx.x;
    if (e >= N_EDGES) return;
    int mbool = flags[0], i64 = flags[1];
    if (!edge_mask(maskp, mbool, e)) return;
    float wv = ea[e];
    if (wv == 0.0f) return;
    int c = idx_col(idx, i64, e);
    if ((unsigned)c >= N_NODES) return;
    atomicAdd(&deg[c], wv);
    atomicAdd(&cnt[c], 1);
}

// deg -> dinv in place
__global__ void k_dinv(float* deg) {
    int i = blockIdx.x * blockDim.x + threadIdx.x;
    if (i >= N_NODES) return;
    float d = deg[i];
    deg[i] = (d > 0.0f) ? rsqrtf(d) : 0.0f;
}

// ---------------------------------------------------------------------------
// Multi-block exclusive scan (R5 post-mortem: single-block scan was 230 µs at
// 0.15% occupancy — 36% of runtime). 3 phases, each fully parallel / tiny.
// ---------------------------------------------------------------------------
// A: partial[b] = sum of cnt[b*1024 .. b*1024+1023]
__global__ void k_scan_a(const int* __restrict__ cnt, int* __restrict__ partial) {
    __shared__ int sh[256];
    int tid = threadIdx.x;
    int base = blockIdx.x * SCAN_CHUNK + tid * 4;
    int s = 0;
#pragma unroll
    for (int k = 0; k < 4; ++k) {
        int i = base + k;
        if (i < N_NODES) s += cnt[i];
    }
    sh[tid] = s;
    __syncthreads();
    for (int d = 128; d > 0; d >>= 1) {
        if (tid < d) sh[tid] += sh[tid + d];
        __syncthreads();
    }
    if (tid == 0) partial[blockIdx.x] = sh[0];
}

// B: exclusive-scan the 98 partials in place; row_ptr[N] = grand total.
__global__ void k_scan_b(int* __restrict__ partial, int* __restrict__ row_ptr) {
    __shared__ int sh[128];
    int tid = threadIdx.x;                     // 128 threads
    int v = (tid < NPART) ? partial[tid] : 0;
    sh[tid] = v;
    __syncthreads();
    for (int d = 1; d < 128; d <<= 1) {
        int t = (tid >= d) ? sh[tid - d] : 0;
        __syncthreads();
        sh[tid] += t;
        __syncthreads();
    }
    if (tid < NPART) partial[tid] = sh[tid] - v;   // exclusive
    if (tid == 127) row_ptr[N_NODES] = sh[127];    // total
}

// C: block-local scan + partial offset -> row_ptr[i]; zero cnt (fill cursor).
__global__ void k_scan_c(int* __restrict__ cnt, const int* __restrict__ partial,
                         int* __restrict__ row_ptr) {
    __shared__ int sh[256];
    int tid = threadIdx.x;
    int base = blockIdx.x * SCAN_CHUNK + tid * 4;
    int v[4];
    int s = 0;
#pragma unroll
    for (int k = 0; k < 4; ++k) {
        int i = base + k;
        v[k] = (i < N_NODES) ? cnt[i] : 0;
        s += v[k];
    }
    sh[tid] = s;
    __syncthreads();
    for (int d = 1; d < 256; d <<= 1) {
        int t = (tid >= d) ? sh[tid - d] : 0;
        __syncthreads();
        sh[tid] += t;
        __syncthreads();
    }
    int off = partial[blockIdx.x] + sh[tid] - s;   // exclusive for this thread
#pragma unroll
    for (int k = 0; k < 4; ++k) {
        int i = base + k;
        if (i < N_NODES) { row_ptr[i] = off; cnt[i] = 0; off += v[k]; }
    }
}

// Fill CSR: for each active edge, slot p = row_ptr[col] + cursor[col]++.
// Inserts EXACTLY cnt[col] entries per node (OOB rows insert nm=0) so
// row_ptr[n+1] is a valid end pointer. csr entry packs (norm bits, src row).
// Bounds-check p: latent mismatch shows as absmax error, never a fault.
__global__ void k_fill(const float* __restrict__ ea, const void* maskp,
                       const int* __restrict__ idx, const int* __restrict__ flags,
                       const float* __restrict__ dinv, const int* __restrict__ row_ptr,
                       int* __restrict__ cursor, int2* __restrict__ csr) {
    int e = blockIdx.x * blockDim.x + threadIdx.x;
    if (e >= N_EDGES) return;
    int mbool = flags[0], i64 = flags[1];
    if (!edge_mask(maskp, mbool, e)) return;
    float wv = ea[e];
    if (wv == 0.0f) return;
    int c = idx_col(idx, i64, e);
    if ((unsigned)c >= N_NODES) return;
    int r = idx_row(idx, i64, e);
    int rok = (unsigned)r < N_NODES;
    float nm = dinv[c] * wv * (rok ? dinv[r] : 0.0f);
    int p = row_ptr[c] + atomicAdd(&cursor[c], 1);
    if ((unsigned)p < N_EDGES)
        csr[p] = make_int2(__float_as_int(nm), rok ? r : 0);
}

// One 64-lane wave per node, lane = dim. Register accumulation, no atomics.
// mode 0: hdst=s, acc=ALPHA*(x+s)   (layer 1, src = x)
// mode 1: hdst=s, acc+=ALPHA*s      (layer 2)
// mode 2: acc+=ALPHA*s              (layer 3, no hdst)
// Clamped indirect reads — can never fault.
__global__ __launch_bounds__(256) void k_gather(
        const int* __restrict__ row_ptr, const int2* __restrict__ csr,
        const float* __restrict__ hsrc, float* __restrict__ hdst,
        const float* __restrict__ x, float* __restrict__ acc, int mode) {
    int t = blockIdx.x * blockDim.x + threadIdx.x;
    int n = t >> 6;
    int d = t & 63;
    if (n >= N_NODES) return;
    int total = row_ptr[N_NODES];
    if (total > N_EDGES) total = N_EDGES;
    int beg = row_ptr[n], end = row_ptr[n + 1];
    if (beg < 0) beg = 0;
    if (end > total) end = total;
    float s = 0.0f;
    for (int j = beg; j < end; ++j) {
        int2 p = csr[j];                       // wave-uniform -> broadcast
        if ((unsigned)p.y >= N_NODES) continue;
        s += __int_as_float(p.x) * hsrc[(size_t)p.y * EMB + d];
    }
    size_t o = (size_t)n * EMB + d;
    if (mode == 0)      { hdst[o] = s; acc[o] = ALPHA * (x[o] + s); }
    else if (mode == 1) { hdst[o] = s; acc[o] += ALPHA * s; }
    else                { acc[o] += ALPHA * s; }
}

extern "C" void kernel_launch(void* const* d_in, const int* in_sizes, int n_in,
                              void* d_out, int out_size, void* d_ws, size_t ws_size,
                              hipStream_t stream) {
    const float* x   = (const float*)d_in[0];
    const float* ea  = (const float*)d_in[1];
    const int*   idx = (const int*)d_in[2];
    const void*  msk = d_in[3];
    float*       acc = (float*)d_out;   // fp32 output doubles as the accumulator

    char* ws = (char*)d_ws;
    size_t off = 0;
    auto alloc = [&](size_t bytes) -> void* {
        void* p = ws + off;
        off = (off + bytes + 255) & ~(size_t)255;
        return p;
    };
    int*   flags   = (int*)  alloc(64);
    float* deg     = (float*)alloc(sizeof(float) * N_NODES);      // then dinv
    int*   cnt     = (int*)  alloc(sizeof(int)   * N_NODES);      // then cursor
    int*   row_ptr = (int*)  alloc(sizeof(int)   * (N_NODES + 1));
    int*   partial = (int*)  alloc(sizeof(int)   * NPART);
    int2*  csr     = (int2*) alloc(sizeof(int2)  * N_EDGES);
    float* hA      = (float*)alloc(sizeof(float) * (size_t)N_NODES * EMB);
    float* hB      = (float*)alloc(sizeof(float) * (size_t)N_NODES * EMB);

    const int B = 256;
    const int gE = (N_EDGES + B - 1) / B;
    const int gN = (N_NODES + B - 1) / B;
    const int gG = (N_NODES * EMB + B - 1) / B;   // 25000 blocks, 1 wave/node

    // deg and cnt are adjacent (modulo 256-pad) -> one memset covers both.
    hipMemsetAsync(deg, 0, (size_t)((char*)row_ptr - (char*)deg), stream);
    k_detect<<<1, 256, 0, stream>>>((const unsigned char*)msk, idx, flags);
    k_degw  <<<gE, B, 0, stream>>>(ea, msk, idx, flags, deg, cnt);
    k_dinv  <<<gN, B, 0, stream>>>(deg);
    k_scan_a<<<NPART, 256, 0, stream>>>(cnt, partial);
    k_scan_b<<<1, 128, 0, stream>>>(partial, row_ptr);
    k_scan_c<<<NPART, 256, 0, stream>>>(cnt, partial, row_ptr);
    k_fill  <<<gE, B, 0, stream>>>(ea, msk, idx, flags, deg, row_ptr, cnt, csr);

    k_gather<<<gG, B, 0, stream>>>(row_ptr, csr, x,  hA, x, acc, 0);
    k_gather<<<gG, B, 0, stream>>>(row_ptr, csr, hA, hB, x, acc, 1);
    k_gather<<<gG, B, 0, stream>>>(row_ptr, csr, hB, hB, x, acc, 2);
}

// Round 7
// 338.536 us; speedup vs baseline: 6.0805x; 1.2447x over previous
//
#include <hip/hip_runtime.h>
#include <hip/hip_bf16.h>

#define N_NODES 100000
#define EMB     64
#define N_EDGES 1200000
#define ALPHA   0.25f
#define SCAN_CHUNK 1024
#define NPART ((N_NODES + SCAN_CHUNK - 1) / SCAN_CHUNK)   // 98

// ---------------------------------------------------------------------------
// Format detection — SAMPLED (R2: full scan was 1.4-2.0 ms @ 0.05% occupancy).
// flags[0] = 1 if mask is 1-byte bool;  flags[1] = 1 if indices are int64.
// ---------------------------------------------------------------------------
__global__ void k_detect(const unsigned char* maskB, const int* idx, int* flags) {
    __shared__ int sm, si;
    if (threadIdx.x == 0) { sm = 0; si = 0; }
    __syncthreads();
    int m = 0, iv = 0;
    for (int i = threadIdx.x; i < 16384; i += blockDim.x)
        if ((i & 3) && maskB[i]) m = 1;
    for (int i = threadIdx.x; i < 4096; i += blockDim.x)
        if (idx[2 * i + 1] != 0) iv = 1;
    if (m)  atomicOr(&sm, 1);
    if (iv) atomicOr(&si, 1);
    __syncthreads();
    if (threadIdx.x == 0) { flags[0] = sm; flags[1] = si ? 0 : 1; }
}

__device__ __forceinline__ int idx_row(const int* idx, int i64, int e) {
    return i64 ? idx[2 * e] : idx[e];
}
__device__ __forceinline__ int idx_col(const int* idx, int i64, int e) {
    return i64 ? idx[2 * (N_EDGES + e)] : idx[N_EDGES + e];
}
__device__ __forceinline__ int edge_mask(const void* maskp, int mbool, int e) {
    return mbool ? (int)((const unsigned char*)maskp)[e] : ((const int*)maskp)[e];
}

// Histogram pass: deg[col] += w (weighted degree), cnt[col] += 1 (CSR counts).
__global__ void k_degw(const float* __restrict__ ea, const void* maskp,
                       const int* __restrict__ idx, const int* __restrict__ flags,
                       float* __restrict__ deg, int* __restrict__ cnt) {
    int e = blockIdx.x * blockDim.x + threadIdx.x;
    if (e >= N_EDGES) return;
    int mbool = flags[0], i64 = flags[1];
    if (!edge_mask(maskp, mbool, e)) return;
    float wv = ea[e];
    if (wv == 0.0f) return;
    int c = idx_col(idx, i64, e);
    if ((unsigned)c >= N_NODES) return;
    atomicAdd(&deg[c], wv);
    atomicAdd(&cnt[c], 1);
}

// deg -> dinv in place
__global__ void k_dinv(float* deg) {
    int i = blockIdx.x * blockDim.x + threadIdx.x;
    if (i >= N_NODES) return;
    float d = deg[i];
    deg[i] = (d > 0.0f) ? rsqrtf(d) : 0.0f;
}

// ---------------------------------------------------------------------------
// Multi-block exclusive scan (R5: single-block scan was 230 µs @ 0.15% occ).
// ---------------------------------------------------------------------------
__global__ void k_scan_a(const int* __restrict__ cnt, int* __restrict__ partial) {
    __shared__ int sh[256];
    int tid = threadIdx.x;
    int base = blockIdx.x * SCAN_CHUNK + tid * 4;
    int s = 0;
#pragma unroll
    for (int k = 0; k < 4; ++k) {
        int i = base + k;
        if (i < N_NODES) s += cnt[i];
    }
    sh[tid] = s;
    __syncthreads();
    for (int d = 128; d > 0; d >>= 1) {
        if (tid < d) sh[tid] += sh[tid + d];
        __syncthreads();
    }
    if (tid == 0) partial[blockIdx.x] = sh[0];
}

__global__ void k_scan_b(int* __restrict__ partial, int* __restrict__ row_ptr) {
    __shared__ int sh[128];
    int tid = threadIdx.x;                     // 128 threads
    int v = (tid < NPART) ? partial[tid] : 0;
    sh[tid] = v;
    __syncthreads();
    for (int d = 1; d < 128; d <<= 1) {
        int t = (tid >= d) ? sh[tid - d] : 0;
        __syncthreads();
        sh[tid] += t;
        __syncthreads();
    }
    if (tid < NPART) partial[tid] = sh[tid] - v;   // exclusive
    if (tid == 127) row_ptr[N_NODES] = sh[127];    // total
}

__global__ void k_scan_c(int* __restrict__ cnt, const int* __restrict__ partial,
                         int* __restrict__ row_ptr) {
    __shared__ int sh[256];
    int tid = threadIdx.x;
    int base = blockIdx.x * SCAN_CHUNK + tid * 4;
    int v[4];
    int s = 0;
#pragma unroll
    for (int k = 0; k < 4; ++k) {
        int i = base + k;
        v[k] = (i < N_NODES) ? cnt[i] : 0;
        s += v[k];
    }
    sh[tid] = s;
    __syncthreads();
    for (int d = 1; d < 256; d <<= 1) {
        int t = (tid >= d) ? sh[tid - d] : 0;
        __syncthreads();
        sh[tid] += t;
        __syncthreads();
    }
    int off = partial[blockIdx.x] + sh[tid] - s;   // exclusive for this thread
#pragma unroll
    for (int k = 0; k < 4; ++k) {
        int i = base + k;
        if (i < N_NODES) { row_ptr[i] = off; cnt[i] = 0; off += v[k]; }
    }
}

// Fill CSR: slot p = row_ptr[col] + cursor[col]++. Inserts EXACTLY cnt[col]
// entries per node (OOB rows insert nm=0, src=0) so every csr entry in
// [row_ptr[n], row_ptr[n+1]) has src in [0,N). Bounds-check p: any latent
// mismatch shows as absmax error, never a fault.
__global__ void k_fill(const float* __restrict__ ea, const void* maskp,
                       const int* __restrict__ idx, const int* __restrict__ flags,
                       const float* __restrict__ dinv, const int* __restrict__ row_ptr,
                       int* __restrict__ cursor, int2* __restrict__ csr) {
    int e = blockIdx.x * blockDim.x + threadIdx.x;
    if (e >= N_EDGES) return;
    int mbool = flags[0], i64 = flags[1];
    if (!edge_mask(maskp, mbool, e)) return;
    float wv = ea[e];
    if (wv == 0.0f) return;
    int c = idx_col(idx, i64, e);
    if ((unsigned)c >= N_NODES) return;
    int r = idx_row(idx, i64, e);
    int rok = (unsigned)r < N_NODES;
    float nm = dinv[c] * wv * (rok ? dinv[r] : 0.0f);
    int p = row_ptr[c] + atomicAdd(&cursor[c], 1);
    if ((unsigned)p < N_EDGES)
        csr[p] = make_int2(__float_as_int(nm), rok ? r : 0);
}

// One 64-lane wave per node, lane = dim. Register accumulation, no atomics.
// R6 post-mortem: loop was a serial load->gather dependent chain (~6 iters,
// VALUBusy 12%, HBM 20% -> latency-bound). Unroll x4: batch 4 csr entries +
// 4 independent row gathers per round, 3x shorter dependent chain.
// p.y is in [0,N) by construction; min() clamp keeps loads fault-proof
// without a branch.
// mode 0: hdst=s, acc=ALPHA*(x+s); mode 1: hdst=s, acc+=ALPHA*s;
// mode 2: acc+=ALPHA*s.
__global__ __launch_bounds__(256) void k_gather(
        const int* __restrict__ row_ptr, const int2* __restrict__ csr,
        const float* __restrict__ hsrc, float* __restrict__ hdst,
        const float* __restrict__ x, float* __restrict__ acc, int mode) {
    int t = blockIdx.x * blockDim.x + threadIdx.x;
    int n = t >> 6;
    int d = t & 63;
    if (n >= N_NODES) return;
    int beg = row_ptr[n], end = row_ptr[n + 1];
    if (beg < 0) beg = 0;
    if (end > N_EDGES) end = N_EDGES;
    float s = 0.0f;
    int j = beg;
    for (; j + 4 <= end; j += 4) {
        int2 p0 = csr[j + 0];
        int2 p1 = csr[j + 1];
        int2 p2 = csr[j + 2];
        int2 p3 = csr[j + 3];
        int r0 = min((unsigned)p0.y, (unsigned)(N_NODES - 1));
        int r1 = min((unsigned)p1.y, (unsigned)(N_NODES - 1));
        int r2 = min((unsigned)p2.y, (unsigned)(N_NODES - 1));
        int r3 = min((unsigned)p3.y, (unsigned)(N_NODES - 1));
        float v0 = hsrc[(size_t)r0 * EMB + d];
        float v1 = hsrc[(size_t)r1 * EMB + d];
        float v2 = hsrc[(size_t)r2 * EMB + d];
        float v3 = hsrc[(size_t)r3 * EMB + d];
        s += __int_as_float(p0.x) * v0;
        s += __int_as_float(p1.x) * v1;
        s += __int_as_float(p2.x) * v2;
        s += __int_as_float(p3.x) * v3;
    }
    for (; j < end; ++j) {
        int2 p = csr[j];
        int r = min((unsigned)p.y, (unsigned)(N_NODES - 1));
        s += __int_as_float(p.x) * hsrc[(size_t)r * EMB + d];
    }
    size_t o = (size_t)n * EMB + d;
    if (mode == 0)      { hdst[o] = s; acc[o] = ALPHA * (x[o] + s); }
    else if (mode == 1) { hdst[o] = s; acc[o] += ALPHA * s; }
    else                { acc[o] += ALPHA * s; }
}

extern "C" void kernel_launch(void* const* d_in, const int* in_sizes, int n_in,
                              void* d_out, int out_size, void* d_ws, size_t ws_size,
                              hipStream_t stream) {
    const float* x   = (const float*)d_in[0];
    const float* ea  = (const float*)d_in[1];
    const int*   idx = (const int*)d_in[2];
    const void*  msk = d_in[3];
    float*       acc = (float*)d_out;   // fp32 output doubles as the accumulator

    char* ws = (char*)d_ws;
    size_t off = 0;
    auto alloc = [&](size_t bytes) -> void* {
        void* p = ws + off;
        off = (off + bytes + 255) & ~(size_t)255;
        return p;
    };
    int*   flags   = (int*)  alloc(64);
    float* deg     = (float*)alloc(sizeof(float) * N_NODES);      // then dinv
    int*   cnt     = (int*)  alloc(sizeof(int)   * N_NODES);      // then cursor
    int*   row_ptr = (int*)  alloc(sizeof(int)   * (N_NODES + 1));
    int*   partial = (int*)  alloc(sizeof(int)   * NPART);
    int2*  csr     = (int2*) alloc(sizeof(int2)  * N_EDGES);
    float* hA      = (float*)alloc(sizeof(float) * (size_t)N_NODES * EMB);
    float* hB      = (float*)alloc(sizeof(float) * (size_t)N_NODES * EMB);

    const int B = 256;
    const int gE = (N_EDGES + B - 1) / B;
    const int gN = (N_NODES + B - 1) / B;
    const int gG = (N_NODES * EMB + B - 1) / B;   // 25000 blocks, 1 wave/node

    // deg and cnt are adjacent (modulo 256-pad) -> one memset covers both.
    hipMemsetAsync(deg, 0, (size_t)((char*)row_ptr - (char*)deg), stream);
    k_detect<<<1, 256, 0, stream>>>((const unsigned char*)msk, idx, flags);
    k_degw  <<<gE, B, 0, stream>>>(ea, msk, idx, flags, deg, cnt);
    k_dinv  <<<gN, B, 0, stream>>>(deg);
    k_scan_a<<<NPART, 256, 0, stream>>>(cnt, partial);
    k_scan_b<<<1, 128, 0, stream>>>(partial, row_ptr);
    k_scan_c<<<NPART, 256, 0, stream>>>(cnt, partial, row_ptr);
    k_fill  <<<gE, B, 0, stream>>>(ea, msk, idx, flags, deg, row_ptr, cnt, csr);

    k_gather<<<gG, B, 0, stream>>>(row_ptr, csr, x,  hA, x, acc, 0);
    k_gather<<<gG, B, 0, stream>>>(row_ptr, csr, hA, hB, x, acc, 1);
    k_gather<<<gG, B, 0, stream>>>(row_ptr, csr, hB, hB, x, acc, 2);
}

// Round 8
// 304.315 us; speedup vs baseline: 6.7643x; 1.1125x over previous
//
#include <hip/hip_runtime.h>
#include <hip/hip_bf16.h>

#define N_NODES 100000
#define EMB     64
#define N_EDGES 1200000
#define ALPHA   0.25f
#define SCAN_CHUNK 1024
#define NPART ((N_NODES + SCAN_CHUNK - 1) / SCAN_CHUNK)   // 98

// ---------------------------------------------------------------------------
// Format detection — SAMPLED (R2: full scan was 1.4-2.0 ms @ 0.05% occupancy).
// flags[0] = 1 if mask is 1-byte bool;  flags[1] = 1 if indices are int64.
// ---------------------------------------------------------------------------
__global__ void k_detect(const unsigned char* maskB, const int* idx, int* flags) {
    __shared__ int sm, si;
    if (threadIdx.x == 0) { sm = 0; si = 0; }
    __syncthreads();
    int m = 0, iv = 0;
    for (int i = threadIdx.x; i < 16384; i += blockDim.x)
        if ((i & 3) && maskB[i]) m = 1;
    for (int i = threadIdx.x; i < 4096; i += blockDim.x)
        if (idx[2 * i + 1] != 0) iv = 1;
    if (m)  atomicOr(&sm, 1);
    if (iv) atomicOr(&si, 1);
    __syncthreads();
    if (threadIdx.x == 0) { flags[0] = sm; flags[1] = si ? 0 : 1; }
}

__device__ __forceinline__ int idx_row(const int* idx, int i64, int e) {
    return i64 ? idx[2 * e] : idx[e];
}
__device__ __forceinline__ int idx_col(const int* idx, int i64, int e) {
    return i64 ? idx[2 * (N_EDGES + e)] : idx[N_EDGES + e];
}
__device__ __forceinline__ int edge_mask(const void* maskp, int mbool, int e) {
    return mbool ? (int)((const unsigned char*)maskp)[e] : ((const int*)maskp)[e];
}

// R7 post-mortem: k_degw was atomic-write-through-bound (37.5 MB WRITE for
// 800 KB of histograms — each device-scope atomic is a ~32 B memory-side
// write). Cut 2.4M atomics to 600k: ONE int atomic per active edge, whose
// return value (the edge's rank within its node) replaces the fill cursor;
// weighted degree is later derived from the CSR slices with zero atomics.
__global__ void k_hist(const float* __restrict__ ea, const void* maskp,
                       const int* __restrict__ idx, const int* __restrict__ flags,
                       int* __restrict__ cnt, int* __restrict__ rank) {
    int e = blockIdx.x * blockDim.x + threadIdx.x;
    if (e >= N_EDGES) return;
    int mbool = flags[0], i64 = flags[1];
    if (!edge_mask(maskp, mbool, e)) return;
    float wv = ea[e];
    if (wv == 0.0f) return;
    int c = idx_col(idx, i64, e);
    if ((unsigned)c >= N_NODES) return;
    rank[e] = atomicAdd(&cnt[c], 1);
}

// ---------------------------------------------------------------------------
// Multi-block exclusive scan (R5: single-block scan was 230 µs @ 0.15% occ).
// ---------------------------------------------------------------------------
__global__ void k_scan_a(const int* __restrict__ cnt, int* __restrict__ partial) {
    __shared__ int sh[256];
    int tid = threadIdx.x;
    int base = blockIdx.x * SCAN_CHUNK + tid * 4;
    int s = 0;
#pragma unroll
    for (int k = 0; k < 4; ++k) {
        int i = base + k;
        if (i < N_NODES) s += cnt[i];
    }
    sh[tid] = s;
    __syncthreads();
    for (int d = 128; d > 0; d >>= 1) {
        if (tid < d) sh[tid] += sh[tid + d];
        __syncthreads();
    }
    if (tid == 0) partial[blockIdx.x] = sh[0];
}

__global__ void k_scan_b(int* __restrict__ partial, int* __restrict__ row_ptr) {
    __shared__ int sh[128];
    int tid = threadIdx.x;                     // 128 threads
    int v = (tid < NPART) ? partial[tid] : 0;
    sh[tid] = v;
    __syncthreads();
    for (int d = 1; d < 128; d <<= 1) {
        int t = (tid >= d) ? sh[tid - d] : 0;
        __syncthreads();
        sh[tid] += t;
        __syncthreads();
    }
    if (tid < NPART) partial[tid] = sh[tid] - v;   // exclusive
    if (tid == 127) row_ptr[N_NODES] = sh[127];    // total
}

__global__ void k_scan_c(const int* __restrict__ cnt, const int* __restrict__ partial,
                         int* __restrict__ row_ptr) {
    __shared__ int sh[256];
    int tid = threadIdx.x;
    int base = blockIdx.x * SCAN_CHUNK + tid * 4;
    int v[4];
    int s = 0;
#pragma unroll
    for (int k = 0; k < 4; ++k) {
        int i = base + k;
        v[k] = (i < N_NODES) ? cnt[i] : 0;
        s += v[k];
    }
    sh[tid] = s;
    __syncthreads();
    for (int d = 1; d < 256; d <<= 1) {
        int t = (tid >= d) ? sh[tid - d] : 0;
        __syncthreads();
        sh[tid] += t;
        __syncthreads();
    }
    int off = partial[blockIdx.x] + sh[tid] - s;   // exclusive for this thread
#pragma unroll
    for (int k = 0; k < 4; ++k) {
        int i = base + k;
        if (i < N_NODES) { row_ptr[i] = off; off += v[k]; }
    }
}

// Fill CSR — ATOMIC-FREE: slot p = row_ptr[col] + rank[e]. hist and fill use
// the identical predicate, so ranks 0..cnt[c]-1 biject onto the slice and csr
// is fully written. Entry = (w bits, src row); norm is fixed up after deg.
// Bounds-check p: any latent mismatch shows as absmax error, never a fault.
__global__ void k_fill(const float* __restrict__ ea, const void* maskp,
                       const int* __restrict__ idx, const int* __restrict__ flags,
                       const int* __restrict__ row_ptr, const int* __restrict__ rank,
                       int2* __restrict__ csr) {
    int e = blockIdx.x * blockDim.x + threadIdx.x;
    if (e >= N_EDGES) return;
    int mbool = flags[0], i64 = flags[1];
    if (!edge_mask(maskp, mbool, e)) return;
    float wv = ea[e];
    if (wv == 0.0f) return;
    int c = idx_col(idx, i64, e);
    if ((unsigned)c >= N_NODES) return;
    int r = idx_row(idx, i64, e);
    int rok = (unsigned)r < N_NODES;
    int p = row_ptr[c] + rank[e];
    if ((unsigned)p < N_EDGES)
        csr[p] = make_int2(__float_as_int(rok ? wv : 0.0f), rok ? r : 0);
}

// Weighted degree from CSR slices (streaming, no atomics) -> dinv in place.
__global__ void k_deg(const int* __restrict__ row_ptr, const int2* __restrict__ csr,
                      float* __restrict__ dinv) {
    int n = blockIdx.x * blockDim.x + threadIdx.x;
    if (n >= N_NODES) return;
    int beg = row_ptr[n], end = row_ptr[n + 1];
    if (beg < 0) beg = 0;
    if (end > N_EDGES) end = N_EDGES;
    float s = 0.0f;
    for (int p = beg; p < end; ++p) s += __int_as_float(csr[p].x);
    dinv[n] = (s > 0.0f) ? rsqrtf(s) : 0.0f;
}

// In-place norm fixup: csr[p].x = dinv[n] * w * dinv[r]. dinv is 400 KB,
// L2-hot; slices contiguous. Keeps the gather kernels identical to R7.
__global__ void k_normfix(const int* __restrict__ row_ptr, const float* __restrict__ dinv,
                          int2* __restrict__ csr) {
    int n = blockIdx.x * blockDim.x + threadIdx.x;
    if (n >= N_NODES) return;
    int beg = row_ptr[n], end = row_ptr[n + 1];
    if (beg < 0) beg = 0;
    if (end > N_EDGES) end = N_EDGES;
    float dn = dinv[n];
    for (int p = beg; p < end; ++p) {
        int2 en = csr[p];
        int r = min((unsigned)en.y, (unsigned)(N_NODES - 1));
        csr[p].x = __float_as_int(__int_as_float(en.x) * dn * dinv[r]);
    }
}

// One 64-lane wave per node, lane = dim. Register accumulation, no atomics.
// R6: x4 unroll batches 4 independent row gathers per round (latency-bound
// loop, 3x shorter dependent chain). min() clamp keeps loads fault-proof.
// mode 0: hdst=s, acc=ALPHA*(x+s); mode 1: hdst=s, acc+=ALPHA*s;
// mode 2: acc+=ALPHA*s.
__global__ __launch_bounds__(256) void k_gather(
        const int* __restrict__ row_ptr, const int2* __restrict__ csr,
        const float* __restrict__ hsrc, float* __restrict__ hdst,
        const float* __restrict__ x, float* __restrict__ acc, int mode) {
    int t = blockIdx.x * blockDim.x + threadIdx.x;
    int n = t >> 6;
    int d = t & 63;
    if (n >= N_NODES) return;
    int beg = row_ptr[n], end = row_ptr[n + 1];
    if (beg < 0) beg = 0;
    if (end > N_EDGES) end = N_EDGES;
    float s = 0.0f;
    int j = beg;
    for (; j + 4 <= end; j += 4) {
        int2 p0 = csr[j + 0];
        int2 p1 = csr[j + 1];
        int2 p2 = csr[j + 2];
        int2 p3 = csr[j + 3];
        int r0 = min((unsigned)p0.y, (unsigned)(N_NODES - 1));
        int r1 = min((unsigned)p1.y, (unsigned)(N_NODES - 1));
        int r2 = min((unsigned)p2.y, (unsigned)(N_NODES - 1));
        int r3 = min((unsigned)p3.y, (unsigned)(N_NODES - 1));
        float v0 = hsrc[(size_t)r0 * EMB + d];
        float v1 = hsrc[(size_t)r1 * EMB + d];
        float v2 = hsrc[(size_t)r2 * EMB + d];
        float v3 = hsrc[(size_t)r3 * EMB + d];
        s += __int_as_float(p0.x) * v0;
        s += __int_as_float(p1.x) * v1;
        s += __int_as_float(p2.x) * v2;
        s += __int_as_float(p3.x) * v3;
    }
    for (; j < end; ++j) {
        int2 p = csr[j];
        int r = min((unsigned)p.y, (unsigned)(N_NODES - 1));
        s += __int_as_float(p.x) * hsrc[(size_t)r * EMB + d];
    }
    size_t o = (size_t)n * EMB + d;
    if (mode == 0)      { hdst[o] = s; acc[o] = ALPHA * (x[o] + s); }
    else if (mode == 1) { hdst[o] = s; acc[o] += ALPHA * s; }
    else                { acc[o] += ALPHA * s; }
}

extern "C" void kernel_launch(void* const* d_in, const int* in_sizes, int n_in,
                              void* d_out, int out_size, void* d_ws, size_t ws_size,
                              hipStream_t stream) {
    const float* x   = (const float*)d_in[0];
    const float* ea  = (const float*)d_in[1];
    const int*   idx = (const int*)d_in[2];
    const void*  msk = d_in[3];
    float*       acc = (float*)d_out;   // fp32 output doubles as the accumulator

    char* ws = (char*)d_ws;
    size_t off = 0;
    auto alloc = [&](size_t bytes) -> void* {
        void* p = ws + off;
        off = (off + bytes + 255) & ~(size_t)255;
        return p;
    };
    int*   flags   = (int*)  alloc(64);
    int*   cnt     = (int*)  alloc(sizeof(int)   * N_NODES);
    float* dinv    = (float*)alloc(sizeof(float) * N_NODES);
    int*   row_ptr = (int*)  alloc(sizeof(int)   * (N_NODES + 1));
    int*   partial = (int*)  alloc(sizeof(int)   * NPART);
    int*   rank    = (int*)  alloc(sizeof(int)   * N_EDGES);
    int2*  csr     = (int2*) alloc(sizeof(int2)  * N_EDGES);
    float* hA      = (float*)alloc(sizeof(float) * (size_t)N_NODES * EMB);
    float* hB      = (float*)alloc(sizeof(float) * (size_t)N_NODES * EMB);

    const int B = 256;
    const int gE = (N_EDGES + B - 1) / B;
    const int gN = (N_NODES + B - 1) / B;
    const int gG = (N_NODES * EMB + B - 1) / B;   // 25000 blocks, 1 wave/node

    hipMemsetAsync(cnt, 0, sizeof(int) * N_NODES, stream);
    k_detect <<<1, 256, 0, stream>>>((const unsigned char*)msk, idx, flags);
    k_hist   <<<gE, B, 0, stream>>>(ea, msk, idx, flags, cnt, rank);
    k_scan_a <<<NPART, 256, 0, stream>>>(cnt, partial);
    k_scan_b <<<1, 128, 0, stream>>>(partial, row_ptr);
    k_scan_c <<<NPART, 256, 0, stream>>>(cnt, partial, row_ptr);
    k_fill   <<<gE, B, 0, stream>>>(ea, msk, idx, flags, row_ptr, rank, csr);
    k_deg    <<<gN, B, 0, stream>>>(row_ptr, csr, dinv);
    k_normfix<<<gN, B, 0, stream>>>(row_ptr, dinv, csr);

    k_gather<<<gG, B, 0, stream>>>(row_ptr, csr, x,  hA, x, acc, 0);
    k_gather<<<gG, B, 0, stream>>>(row_ptr, csr, hA, hB, x, acc, 1);
    k_gather<<<gG, B, 0, stream>>>(row_ptr, csr, hB, hB, x, acc, 2);
}

// Round 9
// 275.681 us; speedup vs baseline: 7.4668x; 1.1039x over previous
//
#include <hip/hip_runtime.h>
#include <hip/hip_bf16.h>

#define N_NODES 100000
#define EMB     64
#define N_EDGES 1200000
#define ALPHA   0.25f
#define SCAN_CHUNK 1024
#define NPART ((N_NODES + SCAN_CHUNK - 1) / SCAN_CHUNK)   // 98

// ---------------------------------------------------------------------------
// Format detection — multi-block sampled (R8: 1-block version serialized the
// pipeline head). Evidence-only flags, OR-accumulated:
//   flags[0] != 0  ->  mask has nonzero bytes at i%4!=0  ->  1-byte bool
//   flags[1] != 0  ->  idx has nonzero odd words         ->  int32 (NOT i64)
// Consumers: mbool = flags[0]!=0; i64 = (flags[1]==0).
// ---------------------------------------------------------------------------
__global__ void k_detect(const unsigned char* maskB, const int* idx, int* flags) {
    int tid = blockIdx.x * blockDim.x + threadIdx.x;    // 64 x 256 = 16384
    int lane = threadIdx.x & 63;
    bool mev = (tid & 3) && maskB[tid];
    if (__any(mev) && lane == 0) atomicOr(&flags[0], 1);
    bool iev = (tid < 4096) && (idx[2 * tid + 1] != 0);
    if (__any(iev) && lane == 0) atomicOr(&flags[1], 1);
}

__device__ __forceinline__ int idx_row(const int* idx, int i64, int e) {
    return i64 ? idx[2 * e] : idx[e];
}
__device__ __forceinline__ int idx_col(const int* idx, int i64, int e) {
    return i64 ? idx[2 * (N_EDGES + e)] : idx[N_EDGES + e];
}
__device__ __forceinline__ int edge_mask(const void* maskp, int mbool, int e) {
    return mbool ? (int)((const unsigned char*)maskp)[e] : ((const int*)maskp)[e];
}

// ONE int atomic per active edge; return value = edge's rank within its node
// (replaces the fill cursor). Weighted degree derived later from CSR slices.
__global__ void k_hist(const float* __restrict__ ea, const void* maskp,
                       const int* __restrict__ idx, const int* __restrict__ flags,
                       int* __restrict__ cnt, int* __restrict__ rank) {
    int e = blockIdx.x * blockDim.x + threadIdx.x;
    if (e >= N_EDGES) return;
    int mbool = flags[0] != 0, i64 = (flags[1] == 0);
    if (!edge_mask(maskp, mbool, e)) return;
    float wv = ea[e];
    if (wv == 0.0f) return;
    int c = idx_col(idx, i64, e);
    if ((unsigned)c >= N_NODES) return;
    rank[e] = atomicAdd(&cnt[c], 1);
}

// R9: single-kernel "scan" — CSR slices need not be globally ordered, only
// disjoint. Each block local-scans its 1024 counts and claims a base offset
// with one atomicAdd on gTotal. Replaces scan_a/b/c (3 dispatches, one of
// them single-block). cnt[] stays live: slice n = [row_start[n],
// row_start[n]+cnt[n]).
__global__ void k_scanx(const int* __restrict__ cnt, int* __restrict__ gTotal,
                        int* __restrict__ row_start) {
    __shared__ int sh[256];
    __shared__ int sbase;
    int tid = threadIdx.x;
    int base = blockIdx.x * SCAN_CHUNK + tid * 4;
    int v[4];
    int s = 0;
#pragma unroll
    for (int k = 0; k < 4; ++k) {
        int i = base + k;
        v[k] = (i < N_NODES) ? cnt[i] : 0;
        s += v[k];
    }
    sh[tid] = s;
    __syncthreads();
    for (int d = 1; d < 256; d <<= 1) {
        int t = (tid >= d) ? sh[tid - d] : 0;
        __syncthreads();
        sh[tid] += t;
        __syncthreads();
    }
    if (tid == 255) sbase = atomicAdd(gTotal, sh[255]);
    __syncthreads();
    int off = sbase + sh[tid] - s;                 // exclusive within block
#pragma unroll
    for (int k = 0; k < 4; ++k) {
        int i = base + k;
        if (i < N_NODES) { row_start[i] = off; off += v[k]; }
    }
}

// Fill CSR — atomic-free: slot p = row_start[col] + rank[e]. hist and fill
// use the identical predicate, so ranks biject onto the slice and csr is
// fully written. Entry = (w bits, src row); norm fixed up after deg.
__global__ void k_fill(const float* __restrict__ ea, const void* maskp,
                       const int* __restrict__ idx, const int* __restrict__ flags,
                       const int* __restrict__ row_start, const int* __restrict__ rank,
                       int2* __restrict__ csr) {
    int e = blockIdx.x * blockDim.x + threadIdx.x;
    if (e >= N_EDGES) return;
    int mbool = flags[0] != 0, i64 = (flags[1] == 0);
    if (!edge_mask(maskp, mbool, e)) return;
    float wv = ea[e];
    if (wv == 0.0f) return;
    int c = idx_col(idx, i64, e);
    if ((unsigned)c >= N_NODES) return;
    int r = idx_row(idx, i64, e);
    int rok = (unsigned)r < N_NODES;
    int p = row_start[c] + rank[e];
    if ((unsigned)p < N_EDGES)
        csr[p] = make_int2(__float_as_int(rok ? wv : 0.0f), rok ? r : 0);
}

__device__ __forceinline__ void slice_bounds(const int* row_start, const int* cnt,
                                             int n, int& beg, int& end) {
    beg = row_start[n];
    if (beg < 0) beg = 0;
    if (beg > N_EDGES) beg = N_EDGES;
    int c = cnt[n];
    if (c < 0) c = 0;
    end = beg + c;
    if (end > N_EDGES) end = N_EDGES;
}

// Weighted degree from CSR slices (streaming, no atomics) -> dinv.
__global__ void k_deg(const int* __restrict__ row_start, const int* __restrict__ cnt,
                      const int2* __restrict__ csr, float* __restrict__ dinv) {
    int n = blockIdx.x * blockDim.x + threadIdx.x;
    if (n >= N_NODES) return;
    int beg, end;
    slice_bounds(row_start, cnt, n, beg, end);
    float s = 0.0f;
    for (int p = beg; p < end; ++p) s += __int_as_float(csr[p].x);
    dinv[n] = (s > 0.0f) ? rsqrtf(s) : 0.0f;
}

// In-place norm fixup: csr[p].x = dinv[n] * w * dinv[r].
__global__ void k_normfix(const int* __restrict__ row_start, const int* __restrict__ cnt,
                          const float* __restrict__ dinv, int2* __restrict__ csr) {
    int n = blockIdx.x * blockDim.x + threadIdx.x;
    if (n >= N_NODES) return;
    int beg, end;
    slice_bounds(row_start, cnt, n, beg, end);
    float dn = dinv[n];
    for (int p = beg; p < end; ++p) {
        int2 en = csr[p];
        int r = min((unsigned)en.y, (unsigned)(N_NODES - 1));
        csr[p].x = __float_as_int(__int_as_float(en.x) * dn * dinv[r]);
    }
}

// One 64-lane wave per node, lane = dim. Register accumulation, no atomics.
// R9: fully masked x4 batches — no serial scalar tail (avg degree ~6 meant
// the tail re-created the dependent-load chain the R6 unroll removed).
// Masked lanes re-load csr[end-1] (L1-hot) with weight forced to 0.
// mode 0: hdst=s, acc=ALPHA*(x+s); mode 1: hdst=s, acc+=ALPHA*s;
// mode 2: acc+=ALPHA*s.
__global__ __launch_bounds__(256) void k_gather(
        const int* __restrict__ row_start, const int* __restrict__ cnt,
        const int2* __restrict__ csr,
        const float* __restrict__ hsrc, float* __restrict__ hdst,
        const float* __restrict__ x, float* __restrict__ acc, int mode) {
    int t = blockIdx.x * blockDim.x + threadIdx.x;
    int n = t >> 6;
    int d = t & 63;
    if (n >= N_NODES) return;
    int beg, end;
    slice_bounds(row_start, cnt, n, beg, end);
    float s = 0.0f;
    for (int j = beg; j < end; j += 4) {
        int last = end - 1;
        int j1 = j + 1 < last ? j + 1 : last;
        int j2 = j + 2 < last ? j + 2 : last;
        int j3 = j + 3 < last ? j + 3 : last;
        int2 p0 = csr[j];
        int2 p1 = csr[j1];
        int2 p2 = csr[j2];
        int2 p3 = csr[j3];
        float w0 = __int_as_float(p0.x);
        float w1 = (j + 1 < end) ? __int_as_float(p1.x) : 0.0f;
        float w2 = (j + 2 < end) ? __int_as_float(p2.x) : 0.0f;
        float w3 = (j + 3 < end) ? __int_as_float(p3.x) : 0.0f;
        int r0 = min((unsigned)p0.y, (unsigned)(N_NODES - 1));
        int r1 = min((unsigned)p1.y, (unsigned)(N_NODES - 1));
        int r2 = min((unsigned)p2.y, (unsigned)(N_NODES - 1));
        int r3 = min((unsigned)p3.y, (unsigned)(N_NODES - 1));
        float v0 = hsrc[(size_t)r0 * EMB + d];
        float v1 = hsrc[(size_t)r1 * EMB + d];
        float v2 = hsrc[(size_t)r2 * EMB + d];
        float v3 = hsrc[(size_t)r3 * EMB + d];
        s += w0 * v0;
        s += w1 * v1;
        s += w2 * v2;
        s += w3 * v3;
    }
    size_t o = (size_t)n * EMB + d;
    if (mode == 0)      { hdst[o] = s; acc[o] = ALPHA * (x[o] + s); }
    else if (mode == 1) { hdst[o] = s; acc[o] += ALPHA * s; }
    else                { acc[o] += ALPHA * s; }
}

extern "C" void kernel_launch(void* const* d_in, const int* in_sizes, int n_in,
                              void* d_out, int out_size, void* d_ws, size_t ws_size,
                              hipStream_t stream) {
    const float* x   = (const float*)d_in[0];
    const float* ea  = (const float*)d_in[1];
    const int*   idx = (const int*)d_in[2];
    const void*  msk = d_in[3];
    float*       acc = (float*)d_out;   // fp32 output doubles as the accumulator

    char* ws = (char*)d_ws;
    size_t off = 0;
    auto alloc = [&](size_t bytes) -> void* {
        void* p = ws + off;
        off = (off + bytes + 255) & ~(size_t)255;
        return p;
    };
    int*   flags     = (int*)  alloc(64);   // flags[0..1] + gTotal at flags[8]
    int*   cnt       = (int*)  alloc(sizeof(int)   * N_NODES);
    int*   row_start = (int*)  alloc(sizeof(int)   * N_NODES);
    float* dinv      = (float*)alloc(sizeof(float) * N_NODES);
    int*   rank      = (int*)  alloc(sizeof(int)   * N_EDGES);
    int2*  csr       = (int2*) alloc(sizeof(int2)  * N_EDGES);
    float* hA        = (float*)alloc(sizeof(float) * (size_t)N_NODES * EMB);
    float* hB        = (float*)alloc(sizeof(float) * (size_t)N_NODES * EMB);
    int*   gTotal    = flags + 8;

    const int B = 256;
    const int gE = (N_EDGES + B - 1) / B;
    const int gN = (N_NODES + B - 1) / B;
    const int gG = (N_NODES * EMB + B - 1) / B;   // 25000 blocks, 1 wave/node

    // flags block + cnt are adjacent in ws -> one memset zeroes both.
    hipMemsetAsync(flags, 0, (size_t)((char*)row_start - (char*)flags), stream);
    k_detect <<<64, 256, 0, stream>>>((const unsigned char*)msk, idx, flags);
    k_hist   <<<gE, B, 0, stream>>>(ea, msk, idx, flags, cnt, rank);
    k_scanx  <<<NPART, 256, 0, stream>>>(cnt, gTotal, row_start);
    k_fill   <<<gE, B, 0, stream>>>(ea, msk, idx, flags, row_start, rank, csr);
    k_deg    <<<gN, B, 0, stream>>>(row_start, cnt, csr, dinv);
    k_normfix<<<gN, B, 0, stream>>>(row_start, cnt, dinv, csr);

    k_gather<<<gG, B, 0, stream>>>(row_start, cnt, csr, x,  hA, x, acc, 0);
    k_gather<<<gG, B, 0, stream>>>(row_start, cnt, csr, hA, hB, x, acc, 1);
    k_gather<<<gG, B, 0, stream>>>(row_start, cnt, csr, hB, hB, x, acc, 2);
}

// Round 10
// 236.300 us; speedup vs baseline: 8.7112x; 1.1667x over previous
//
#include <hip/hip_runtime.h>
#include <hip/hip_bf16.h>

#define N_NODES 100000
#define EMB     64
#define N_EDGES 1200000
#define ALPHA   0.25f
#define SCAN_CHUNK 1024
#define NPART ((N_NODES + SCAN_CHUNK - 1) / SCAN_CHUNK)   // 98

// ---------------------------------------------------------------------------
// Format detection — multi-block sampled. Evidence-only flags, OR-accumulated:
//   flags[0] != 0  ->  mask has nonzero bytes at i%4!=0  ->  1-byte bool
//   flags[1] != 0  ->  idx has nonzero odd words         ->  int32 (NOT i64)
// ---------------------------------------------------------------------------
__global__ void k_detect(const unsigned char* maskB, const int* idx, int* flags) {
    int tid = blockIdx.x * blockDim.x + threadIdx.x;    // 64 x 256 = 16384
    int lane = threadIdx.x & 63;
    bool mev = (tid & 3) && maskB[tid];
    if (__any(mev) && lane == 0) atomicOr(&flags[0], 1);
    bool iev = (tid < 4096) && (idx[2 * tid + 1] != 0);
    if (__any(iev) && lane == 0) atomicOr(&flags[1], 1);
}

__device__ __forceinline__ int idx_row(const int* idx, int i64, int e) {
    return i64 ? idx[2 * e] : idx[e];
}
__device__ __forceinline__ int idx_col(const int* idx, int i64, int e) {
    return i64 ? idx[2 * (N_EDGES + e)] : idx[N_EDGES + e];
}
__device__ __forceinline__ int edge_mask(const void* maskp, int mbool, int e) {
    return mbool ? (int)((const unsigned char*)maskp)[e] : ((const int*)maskp)[e];
}

// ONE int atomic per active edge; return value = edge's rank within its node.
__global__ void k_hist(const float* __restrict__ ea, const void* maskp,
                       const int* __restrict__ idx, const int* __restrict__ flags,
                       int* __restrict__ cnt, int* __restrict__ rank) {
    int e = blockIdx.x * blockDim.x + threadIdx.x;
    if (e >= N_EDGES) return;
    int mbool = flags[0] != 0, i64 = (flags[1] == 0);
    if (!edge_mask(maskp, mbool, e)) return;
    float wv = ea[e];
    if (wv == 0.0f) return;
    int c = idx_col(idx, i64, e);
    if ((unsigned)c >= N_NODES) return;
    rank[e] = atomicAdd(&cnt[c], 1);
}

// Single-kernel scan: slices need only be disjoint, not globally ordered.
// Block local-scans 1024 counts, claims base via one atomicAdd on gTotal.
__global__ void k_scanx(const int* __restrict__ cnt, int* __restrict__ gTotal,
                        int* __restrict__ row_start) {
    __shared__ int sh[256];
    __shared__ int sbase;
    int tid = threadIdx.x;
    int base = blockIdx.x * SCAN_CHUNK + tid * 4;
    int v[4];
    int s = 0;
#pragma unroll
    for (int k = 0; k < 4; ++k) {
        int i = base + k;
        v[k] = (i < N_NODES) ? cnt[i] : 0;
        s += v[k];
    }
    sh[tid] = s;
    __syncthreads();
    for (int d = 1; d < 256; d <<= 1) {
        int t = (tid >= d) ? sh[tid - d] : 0;
        __syncthreads();
        sh[tid] += t;
        __syncthreads();
    }
    if (tid == 255) sbase = atomicAdd(gTotal, sh[255]);
    __syncthreads();
    int off = sbase + sh[tid] - s;                 // exclusive within block
#pragma unroll
    for (int k = 0; k < 4; ++k) {
        int i = base + k;
        if (i < N_NODES) { row_start[i] = off; off += v[k]; }
    }
}

// Fill CSR — atomic-free: slot p = row_start[col] + rank[e].
__global__ void k_fill(const float* __restrict__ ea, const void* maskp,
                       const int* __restrict__ idx, const int* __restrict__ flags,
                       const int* __restrict__ row_start, const int* __restrict__ rank,
                       int2* __restrict__ csr) {
    int e = blockIdx.x * blockDim.x + threadIdx.x;
    if (e >= N_EDGES) return;
    int mbool = flags[0] != 0, i64 = (flags[1] == 0);
    if (!edge_mask(maskp, mbool, e)) return;
    float wv = ea[e];
    if (wv == 0.0f) return;
    int c = idx_col(idx, i64, e);
    if ((unsigned)c >= N_NODES) return;
    int r = idx_row(idx, i64, e);
    int rok = (unsigned)r < N_NODES;
    int p = row_start[c] + rank[e];
    if ((unsigned)p < N_EDGES)
        csr[p] = make_int2(__float_as_int(rok ? wv : 0.0f), rok ? r : 0);
}

__device__ __forceinline__ void slice_bounds(const int* row_start, const int* cnt,
                                             int n, int& beg, int& end) {
    beg = row_start[n];
    if (beg < 0) beg = 0;
    if (beg > N_EDGES) beg = N_EDGES;
    int c = cnt[n];
    if (c < 0) c = 0;
    end = beg + c;
    if (end > N_EDGES) end = N_EDGES;
}

// Weighted degree from CSR slices (streaming, no atomics) -> dinv.
__global__ void k_deg(const int* __restrict__ row_start, const int* __restrict__ cnt,
                      const int2* __restrict__ csr, float* __restrict__ dinv) {
    int n = blockIdx.x * blockDim.x + threadIdx.x;
    if (n >= N_NODES) return;
    int beg, end;
    slice_bounds(row_start, cnt, n, beg, end);
    float s = 0.0f;
    for (int p = beg; p < end; ++p) s += __int_as_float(csr[p].x);
    dinv[n] = (s > 0.0f) ? rsqrtf(s) : 0.0f;
}

// In-place norm fixup: csr[p].x = dinv[n] * w * dinv[r].
__global__ void k_normfix(const int* __restrict__ row_start, const int* __restrict__ cnt,
                          const float* __restrict__ dinv, int2* __restrict__ csr) {
    int n = blockIdx.x * blockDim.x + threadIdx.x;
    if (n >= N_NODES) return;
    int beg, end;
    slice_bounds(row_start, cnt, n, beg, end);
    float dn = dinv[n];
    for (int p = beg; p < end; ++p) {
        int2 en = csr[p];
        int r = min((unsigned)en.y, (unsigned)(N_NODES - 1));
        csr[p].x = __float_as_int(__int_as_float(en.x) * dn * dinv[r]);
    }
}

// R10: vectorized gather — 16 lanes per node, float4 per lane (4 nodes/wave).
// Per edge: 16 dwordx4 loads instead of 64 dword (same bytes, 4x fewer
// instructions); epilogue also dwordx4. csr entry loads broadcast within the
// 16-lane group. Masked batch lanes redirect to row 0 (L1-hot) with w=0.
// Inter-group degree divergence is exec-masked.
// mode 0: hdst=s, acc=ALPHA*(x+s); mode 1: hdst=s, acc+=ALPHA*s;
// mode 2: acc+=ALPHA*s.
__global__ __launch_bounds__(256) void k_gather(
        const int* __restrict__ row_start, const int* __restrict__ cnt,
        const int2* __restrict__ csr,
        const float* __restrict__ hsrc, float* __restrict__ hdst,
        const float* __restrict__ x, float* __restrict__ acc, int mode) {
    int t = blockIdx.x * blockDim.x + threadIdx.x;
    int n = t >> 4;                 // node = 16-lane group
    int q = t & 15;                 // float4 slot within the row
    if (n >= N_NODES) return;
    int beg, end;
    slice_bounds(row_start, cnt, n, beg, end);
    const float4* __restrict__ h4 = (const float4*)hsrc;
    float4 s = make_float4(0.f, 0.f, 0.f, 0.f);
    for (int j = beg; j < end; j += 4) {
        int last = end - 1;
        int j1 = j + 1 < last ? j + 1 : last;
        int j2 = j + 2 < last ? j + 2 : last;
        int j3 = j + 3 < last ? j + 3 : last;
        int2 p0 = csr[j];
        int2 p1 = csr[j1];
        int2 p2 = csr[j2];
        int2 p3 = csr[j3];
        bool a1 = j + 1 < end, a2 = j + 2 < end, a3 = j + 3 < end;
        float w0 = __int_as_float(p0.x);
        float w1 = a1 ? __int_as_float(p1.x) : 0.0f;
        float w2 = a2 ? __int_as_float(p2.x) : 0.0f;
        float w3 = a3 ? __int_as_float(p3.x) : 0.0f;
        int r0 = min((unsigned)p0.y, (unsigned)(N_NODES - 1));
        int r1 = a1 ? min((unsigned)p1.y, (unsigned)(N_NODES - 1)) : 0;
        int r2 = a2 ? min((unsigned)p2.y, (unsigned)(N_NODES - 1)) : 0;
        int r3 = a3 ? min((unsigned)p3.y, (unsigned)(N_NODES - 1)) : 0;
        float4 v0 = h4[(size_t)r0 * 16 + q];
        float4 v1 = h4[(size_t)r1 * 16 + q];
        float4 v2 = h4[(size_t)r2 * 16 + q];
        float4 v3 = h4[(size_t)r3 * 16 + q];
        s.x += w0 * v0.x; s.y += w0 * v0.y; s.z += w0 * v0.z; s.w += w0 * v0.w;
        s.x += w1 * v1.x; s.y += w1 * v1.y; s.z += w1 * v1.z; s.w += w1 * v1.w;
        s.x += w2 * v2.x; s.y += w2 * v2.y; s.z += w2 * v2.z; s.w += w2 * v2.w;
        s.x += w3 * v3.x; s.y += w3 * v3.y; s.z += w3 * v3.z; s.w += w3 * v3.w;
    }
    size_t o = (size_t)n * 16 + q;
    float4* __restrict__ hdst4 = (float4*)hdst;
    float4* __restrict__ acc4  = (float4*)acc;
    if (mode == 0) {
        float4 xv = ((const float4*)x)[o];
        hdst4[o] = s;
        acc4[o] = make_float4(ALPHA * (xv.x + s.x), ALPHA * (xv.y + s.y),
                              ALPHA * (xv.z + s.z), ALPHA * (xv.w + s.w));
    } else if (mode == 1) {
        hdst4[o] = s;
        float4 av = acc4[o];
        acc4[o] = make_float4(av.x + ALPHA * s.x, av.y + ALPHA * s.y,
                              av.z + ALPHA * s.z, av.w + ALPHA * s.w);
    } else {
        float4 av = acc4[o];
        acc4[o] = make_float4(av.x + ALPHA * s.x, av.y + ALPHA * s.y,
                              av.z + ALPHA * s.z, av.w + ALPHA * s.w);
    }
}

extern "C" void kernel_launch(void* const* d_in, const int* in_sizes, int n_in,
                              void* d_out, int out_size, void* d_ws, size_t ws_size,
                              hipStream_t stream) {
    const float* x   = (const float*)d_in[0];
    const float* ea  = (const float*)d_in[1];
    const int*   idx = (const int*)d_in[2];
    const void*  msk = d_in[3];
    float*       acc = (float*)d_out;   // fp32 output doubles as the accumulator

    char* ws = (char*)d_ws;
    size_t off = 0;
    auto alloc = [&](size_t bytes) -> void* {
        void* p = ws + off;
        off = (off + bytes + 255) & ~(size_t)255;
        return p;
    };
    int*   flags     = (int*)  alloc(64);   // flags[0..1] + gTotal at flags[8]
    int*   cnt       = (int*)  alloc(sizeof(int)   * N_NODES);
    int*   row_start = (int*)  alloc(sizeof(int)   * N_NODES);
    float* dinv      = (float*)alloc(sizeof(float) * N_NODES);
    int*   rank      = (int*)  alloc(sizeof(int)   * N_EDGES);
    int2*  csr       = (int2*) alloc(sizeof(int2)  * N_EDGES);
    float* hA        = (float*)alloc(sizeof(float) * (size_t)N_NODES * EMB);
    float* hB        = (float*)alloc(sizeof(float) * (size_t)N_NODES * EMB);
    int*   gTotal    = flags + 8;

    const int B = 256;
    const int gE = (N_EDGES + B - 1) / B;
    const int gN = (N_NODES + B - 1) / B;
    const int gG = (N_NODES * 16 + B - 1) / B;   // 6250 blocks, 16 lanes/node

    // flags block + cnt are adjacent in ws -> one memset zeroes both.
    hipMemsetAsync(flags, 0, (size_t)((char*)row_start - (char*)flags), stream);
    k_detect <<<64, 256, 0, stream>>>((const unsigned char*)msk, idx, flags);
    k_hist   <<<gE, B, 0, stream>>>(ea, msk, idx, flags, cnt, rank);
    k_scanx  <<<NPART, 256, 0, stream>>>(cnt, gTotal, row_start);
    k_fill   <<<gE, B, 0, stream>>>(ea, msk, idx, flags, row_start, rank, csr);
    k_deg    <<<gN, B, 0, stream>>>(row_start, cnt, csr, dinv);
    k_normfix<<<gN, B, 0, stream>>>(row_start, cnt, dinv, csr);

    k_gather<<<gG, B, 0, stream>>>(row_start, cnt, csr, x,  hA, x, acc, 0);
    k_gather<<<gG, B, 0, stream>>>(row_start, cnt, csr, hA, hB, x, acc, 1);
    k_gather<<<gG, B, 0, stream>>>(row_start, cnt, csr, hB, hB, x, acc, 2);
}

// Round 11
// 227.730 us; speedup vs baseline: 9.0391x; 1.0376x over previous
//
#include <hip/hip_runtime.h>
#include <hip/hip_bf16.h>

#define N_NODES 100000
#define EMB     64
#define N_EDGES 1200000
#define ALPHA   0.25f
#define SCAN_CHUNK 1024
#define NPART ((N_NODES + SCAN_CHUNK - 1) / SCAN_CHUNK)   // 98

// ---------------------------------------------------------------------------
// Format detection — multi-block sampled. Evidence-only flags, OR-accumulated:
//   flags[0] != 0  ->  mask has nonzero bytes at i%4!=0  ->  1-byte bool
//   flags[1] != 0  ->  idx has nonzero odd words         ->  int32 (NOT i64)
// ---------------------------------------------------------------------------
__global__ void k_detect(const unsigned char* maskB, const int* idx, int* flags) {
    int tid = blockIdx.x * blockDim.x + threadIdx.x;    // 64 x 256 = 16384
    int lane = threadIdx.x & 63;
    bool mev = (tid & 3) && maskB[tid];
    if (__any(mev) && lane == 0) atomicOr(&flags[0], 1);
    bool iev = (tid < 4096) && (idx[2 * tid + 1] != 0);
    if (__any(iev) && lane == 0) atomicOr(&flags[1], 1);
}

__device__ __forceinline__ int idx_row(const int* idx, int i64, int e) {
    return i64 ? idx[2 * e] : idx[e];
}
__device__ __forceinline__ int idx_col(const int* idx, int i64, int e) {
    return i64 ? idx[2 * (N_EDGES + e)] : idx[N_EDGES + e];
}
__device__ __forceinline__ int edge_mask(const void* maskp, int mbool, int e) {
    return mbool ? (int)((const unsigned char*)maskp)[e] : ((const int*)maskp)[e];
}

// ONE int atomic per active edge; return value = edge's rank within its node.
__global__ void k_hist(const float* __restrict__ ea, const void* maskp,
                       const int* __restrict__ idx, const int* __restrict__ flags,
                       int* __restrict__ cnt, int* __restrict__ rank) {
    int e = blockIdx.x * blockDim.x + threadIdx.x;
    if (e >= N_EDGES) return;
    int mbool = flags[0] != 0, i64 = (flags[1] == 0);
    if (!edge_mask(maskp, mbool, e)) return;
    float wv = ea[e];
    if (wv == 0.0f) return;
    int c = idx_col(idx, i64, e);
    if ((unsigned)c >= N_NODES) return;
    rank[e] = atomicAdd(&cnt[c], 1);
}

// Single-kernel scan: slices need only be disjoint, not globally ordered.
// Block local-scans 1024 counts, claims base via one atomicAdd on gTotal.
__global__ void k_scanx(const int* __restrict__ cnt, int* __restrict__ gTotal,
                        int* __restrict__ row_start) {
    __shared__ int sh[256];
    __shared__ int sbase;
    int tid = threadIdx.x;
    int base = blockIdx.x * SCAN_CHUNK + tid * 4;
    int v[4];
    int s = 0;
#pragma unroll
    for (int k = 0; k < 4; ++k) {
        int i = base + k;
        v[k] = (i < N_NODES) ? cnt[i] : 0;
        s += v[k];
    }
    sh[tid] = s;
    __syncthreads();
    for (int d = 1; d < 256; d <<= 1) {
        int t = (tid >= d) ? sh[tid - d] : 0;
        __syncthreads();
        sh[tid] += t;
        __syncthreads();
    }
    if (tid == 255) sbase = atomicAdd(gTotal, sh[255]);
    __syncthreads();
    int off = sbase + sh[tid] - s;                 // exclusive within block
#pragma unroll
    for (int k = 0; k < 4; ++k) {
        int i = base + k;
        if (i < N_NODES) { row_start[i] = off; off += v[k]; }
    }
}

// Fill CSR — atomic-free: slot p = row_start[col] + rank[e].
__global__ void k_fill(const float* __restrict__ ea, const void* maskp,
                       const int* __restrict__ idx, const int* __restrict__ flags,
                       const int* __restrict__ row_start, const int* __restrict__ rank,
                       int2* __restrict__ csr) {
    int e = blockIdx.x * blockDim.x + threadIdx.x;
    if (e >= N_EDGES) return;
    int mbool = flags[0] != 0, i64 = (flags[1] == 0);
    if (!edge_mask(maskp, mbool, e)) return;
    float wv = ea[e];
    if (wv == 0.0f) return;
    int c = idx_col(idx, i64, e);
    if ((unsigned)c >= N_NODES) return;
    int r = idx_row(idx, i64, e);
    int rok = (unsigned)r < N_NODES;
    int p = row_start[c] + rank[e];
    if ((unsigned)p < N_EDGES)
        csr[p] = make_int2(__float_as_int(rok ? wv : 0.0f), rok ? r : 0);
}

__device__ __forceinline__ void slice_bounds(const int* row_start, const int* cnt,
                                             int n, int& beg, int& end) {
    beg = row_start[n];
    if (beg < 0) beg = 0;
    if (beg > N_EDGES) beg = N_EDGES;
    int c = cnt[n];
    if (c < 0) c = 0;
    end = beg + c;
    if (end > N_EDGES) end = N_EDGES;
}

// Weighted degree from CSR slices (streaming, no atomics) -> dinv.
__global__ void k_deg(const int* __restrict__ row_start, const int* __restrict__ cnt,
                      const int2* __restrict__ csr, float* __restrict__ dinv) {
    int n = blockIdx.x * blockDim.x + threadIdx.x;
    if (n >= N_NODES) return;
    int beg, end;
    slice_bounds(row_start, cnt, n, beg, end);
    float s = 0.0f;
    for (int p = beg; p < end; ++p) s += __int_as_float(csr[p].x);
    dinv[n] = (s > 0.0f) ? rsqrtf(s) : 0.0f;
}

// In-place norm fixup: csr[p].x = dinv[n] * w * dinv[r].
__global__ void k_normfix(const int* __restrict__ row_start, const int* __restrict__ cnt,
                          const float* __restrict__ dinv, int2* __restrict__ csr) {
    int n = blockIdx.x * blockDim.x + threadIdx.x;
    if (n >= N_NODES) return;
    int beg, end;
    slice_bounds(row_start, cnt, n, beg, end);
    float dn = dinv[n];
    for (int p = beg; p < end; ++p) {
        int2 en = csr[p];
        int r = min((unsigned)en.y, (unsigned)(N_NODES - 1));
        csr[p].x = __float_as_int(__int_as_float(en.x) * dn * dinv[r]);
    }
}

// Shared aggregation core: 16 lanes per node, float4 per lane (4 nodes/wave).
// Fully masked x4 batches; masked lanes redirect to row 0 (L1-hot) with w=0.
__device__ __forceinline__ float4 gather_core(
        const int* __restrict__ row_start, const int* __restrict__ cnt,
        const int2* __restrict__ csr, const float4* __restrict__ h4,
        int n, int q) {
    int beg, end;
    slice_bounds(row_start, cnt, n, beg, end);
    float4 s = make_float4(0.f, 0.f, 0.f, 0.f);
    for (int j = beg; j < end; j += 4) {
        int last = end - 1;
        int j1 = j + 1 < last ? j + 1 : last;
        int j2 = j + 2 < last ? j + 2 : last;
        int j3 = j + 3 < last ? j + 3 : last;
        int2 p0 = csr[j];
        int2 p1 = csr[j1];
        int2 p2 = csr[j2];
        int2 p3 = csr[j3];
        bool a1 = j + 1 < end, a2 = j + 2 < end, a3 = j + 3 < end;
        float w0 = __int_as_float(p0.x);
        float w1 = a1 ? __int_as_float(p1.x) : 0.0f;
        float w2 = a2 ? __int_as_float(p2.x) : 0.0f;
        float w3 = a3 ? __int_as_float(p3.x) : 0.0f;
        int r0 = min((unsigned)p0.y, (unsigned)(N_NODES - 1));
        int r1 = a1 ? min((unsigned)p1.y, (unsigned)(N_NODES - 1)) : 0;
        int r2 = a2 ? min((unsigned)p2.y, (unsigned)(N_NODES - 1)) : 0;
        int r3 = a3 ? min((unsigned)p3.y, (unsigned)(N_NODES - 1)) : 0;
        float4 v0 = h4[(size_t)r0 * 16 + q];
        float4 v1 = h4[(size_t)r1 * 16 + q];
        float4 v2 = h4[(size_t)r2 * 16 + q];
        float4 v3 = h4[(size_t)r3 * 16 + q];
        s.x += w0 * v0.x; s.y += w0 * v0.y; s.z += w0 * v0.z; s.w += w0 * v0.w;
        s.x += w1 * v1.x; s.y += w1 * v1.y; s.z += w1 * v1.z; s.w += w1 * v1.w;
        s.x += w2 * v2.x; s.y += w2 * v2.y; s.z += w2 * v2.z; s.w += w2 * v2.w;
        s.x += w3 * v3.x; s.y += w3 * v3.y; s.z += w3 * v3.z; s.w += w3 * v3.w;
    }
    return s;
}

// R11 mid-layer: h_next = A_hat @ h. NO acc traffic (out = alpha*(x+h1+h2+h3)
// is assembled in the last layer) — WRITE halves vs R10's mode 0/1.
__global__ __launch_bounds__(256) void k_gather_mid(
        const int* __restrict__ row_start, const int* __restrict__ cnt,
        const int2* __restrict__ csr,
        const float* __restrict__ hsrc, float* __restrict__ hdst) {
    int t = blockIdx.x * blockDim.x + threadIdx.x;
    int n = t >> 4;
    int q = t & 15;
    if (n >= N_NODES) return;
    float4 s = gather_core(row_start, cnt, csr, (const float4*)hsrc, n, q);
    ((float4*)hdst)[(size_t)n * 16 + q] = s;
}

// R11 last layer: s = A_hat @ h2, then out = ALPHA*(x + h1 + h2 + s) directly
// (streaming dwordx4 reads of x,h1,h2; folding here saves a separate 128 MB
// combine pass).
__global__ __launch_bounds__(256) void k_gather_last(
        const int* __restrict__ row_start, const int* __restrict__ cnt,
        const int2* __restrict__ csr,
        const float* __restrict__ x, const float* __restrict__ h1,
        const float* __restrict__ h2, float* __restrict__ out) {
    int t = blockIdx.x * blockDim.x + threadIdx.x;
    int n = t >> 4;
    int q = t & 15;
    if (n >= N_NODES) return;
    float4 s = gather_core(row_start, cnt, csr, (const float4*)h2, n, q);
    size_t o = (size_t)n * 16 + q;
    float4 xv = ((const float4*)x)[o];
    float4 a1 = ((const float4*)h1)[o];
    float4 a2 = ((const float4*)h2)[o];
    ((float4*)out)[o] = make_float4(
        ALPHA * (xv.x + a1.x + a2.x + s.x),
        ALPHA * (xv.y + a1.y + a2.y + s.y),
        ALPHA * (xv.z + a1.z + a2.z + s.z),
        ALPHA * (xv.w + a1.w + a2.w + s.w));
}

extern "C" void kernel_launch(void* const* d_in, const int* in_sizes, int n_in,
                              void* d_out, int out_size, void* d_ws, size_t ws_size,
                              hipStream_t stream) {
    const float* x   = (const float*)d_in[0];
    const float* ea  = (const float*)d_in[1];
    const int*   idx = (const int*)d_in[2];
    const void*  msk = d_in[3];
    float*       out = (float*)d_out;

    char* ws = (char*)d_ws;
    size_t off = 0;
    auto alloc = [&](size_t bytes) -> void* {
        void* p = ws + off;
        off = (off + bytes + 255) & ~(size_t)255;
        return p;
    };
    int*   flags     = (int*)  alloc(64);   // flags[0..1] + gTotal at flags[8]
    int*   cnt       = (int*)  alloc(sizeof(int)   * N_NODES);
    int*   row_start = (int*)  alloc(sizeof(int)   * N_NODES);
    float* dinv      = (float*)alloc(sizeof(float) * N_NODES);
    int*   rank      = (int*)  alloc(sizeof(int)   * N_EDGES);
    int2*  csr       = (int2*) alloc(sizeof(int2)  * N_EDGES);
    float* hA        = (float*)alloc(sizeof(float) * (size_t)N_NODES * EMB);
    float* hB        = (float*)alloc(sizeof(float) * (size_t)N_NODES * EMB);
    int*   gTotal    = flags + 8;

    const int B = 256;
    const int gE = (N_EDGES + B - 1) / B;
    const int gN = (N_NODES + B - 1) / B;
    const int gG = (N_NODES * 16 + B - 1) / B;   // 6250 blocks, 16 lanes/node

    // flags block + cnt are adjacent in ws -> one memset zeroes both.
    hipMemsetAsync(flags, 0, (size_t)((char*)row_start - (char*)flags), stream);
    k_detect <<<64, 256, 0, stream>>>((const unsigned char*)msk, idx, flags);
    k_hist   <<<gE, B, 0, stream>>>(ea, msk, idx, flags, cnt, rank);
    k_scanx  <<<NPART, 256, 0, stream>>>(cnt, gTotal, row_start);
    k_fill   <<<gE, B, 0, stream>>>(ea, msk, idx, flags, row_start, rank, csr);
    k_deg    <<<gN, B, 0, stream>>>(row_start, cnt, csr, dinv);
    k_normfix<<<gN, B, 0, stream>>>(row_start, cnt, dinv, csr);

    k_gather_mid <<<gG, B, 0, stream>>>(row_start, cnt, csr, x,  hA);
    k_gather_mid <<<gG, B, 0, stream>>>(row_start, cnt, csr, hA, hB);
    k_gather_last<<<gG, B, 0, stream>>>(row_start, cnt, csr, x, hA, hB, out);
}